// Round 16
// baseline (86.156 us; speedup 1.0000x reference)
//
#include <hip/hip_runtime.h>

typedef short s8v __attribute__((ext_vector_type(8)));
typedef float f4v __attribute__((ext_vector_type(4)));
typedef unsigned short u16;
typedef unsigned int   u32;
typedef unsigned long long u64;

#define NHEAD 8
#define FDIM  32   // D/2

__device__ __forceinline__ u16 f2bf(float f) {
    u32 u = __float_as_uint(f);
    u32 r = u + 0x7fffu + ((u >> 16) & 1u);   // round-to-nearest-even
    return (u16)(r >> 16);
}

// Int-width / mask-width detection (floats are f32: proven in R8/R9).
__device__ __forceinline__ void detect_ints(const void* maskp, const void* eidxp,
                                            int lane, int& mbyte, int& i64f) {
    u32 mkw = ((const u32*)maskp)[lane];
    mbyte = (__ballot(mkw > 1u) != 0ull) ? 1 : 0;       // byte-packed bools -> words > 1
    u32 od = ((const u32*)eidxp)[2 * lane + 1];
    i64f = (__ballot(od != 0u) == 0ull) ? 1 : 0;        // int64 -> odd words all zero
}

struct WaveCtx {
    s8v bfrag[2][2];
    float sumWh, b2v, b1c0, b1c1, w2c0, w2c1;
    float wh0, wh1, wh2, wh3;
};

__device__ __forceinline__ WaveCtx setup_wave(int lane,
    const void* W1p, const void* b1p, const void* W2p, const void* b2p, const void* Whp)
{
    WaveCtx w;
    const int c0 = lane & 15;
    const int krow = (lane >> 4) * 8;
    const int hi4  = (lane >> 4) & 1;
    const float* w1 = (const float*)W1p; const float* b1 = (const float*)b1p;
    const float* w2 = (const float*)W2p; const float* b2 = (const float*)b2p;
    const float* wh = (const float*)Whp;
    float WhV[NHEAD]; w.sumWh = 0.f;
    #pragma unroll
    for (int h = 0; h < NHEAD; ++h) { WhV[h] = wh[h]; w.sumWh += WhV[h]; }
    w.b2v = b2[0];
    w.b1c0 = b1[c0]; w.b1c1 = b1[c0 + 16];
    w.w2c0 = w2[c0]; w.w2c1 = w2[c0 + 16];
    #pragma unroll
    for (int cb = 0; cb < 2; ++cb)
        #pragma unroll
        for (int kh = 0; kh < 2; ++kh)
            #pragma unroll
            for (int j = 0; j < 8; ++j) {
                int k = kh * 32 + krow + j;
                w.bfrag[cb][kh][j] = (short)f2bf(w1[k * FDIM + cb * 16 + c0]);
            }
    w.wh0 = hi4 ? WhV[4] : WhV[0];
    w.wh1 = hi4 ? WhV[5] : WhV[1];
    w.wh2 = hi4 ? WhV[6] : WhV[2];
    w.wh3 = hi4 ? WhV[7] : WhV[3];
    return w;
}

__device__ __forceinline__ void load_tile(const float* a32, int edge, int row, int krow,
                                          s8v& a0, s8v& a1)
{
    const size_t rowbase = ((size_t)edge * 8 + (size_t)(row & 7)) * 64 + (size_t)krow;
    const f4v* p = (const f4v*)(a32 + rowbase);   // 32B-aligned
    f4v v0 = p[0], v1 = p[1], v2 = p[8], v3 = p[9];
    #pragma unroll
    for (int j = 0; j < 4; ++j) {
        a0[j]     = (short)f2bf(v0[j]);
        a0[j + 4] = (short)f2bf(v1[j]);
        a1[j]     = (short)f2bf(v2[j]);
        a1[j + 4] = (short)f2bf(v3[j]);
    }
}

// MFMA + MLP epilogue; even edge's att in lanes 0-31, odd edge's in 32-63.
__device__ __forceinline__ float tile_att(const WaveCtx& w, const s8v& a0, const s8v& a1)
{
    f4v C0 = {0.f,0.f,0.f,0.f}, C1 = {0.f,0.f,0.f,0.f};
    C0 = __builtin_amdgcn_mfma_f32_16x16x32_bf16(a0, w.bfrag[0][0], C0, 0, 0, 0);
    C0 = __builtin_amdgcn_mfma_f32_16x16x32_bf16(a1, w.bfrag[0][1], C0, 0, 0, 0);
    C1 = __builtin_amdgcn_mfma_f32_16x16x32_bf16(a0, w.bfrag[1][0], C1, 0, 0, 0);
    C1 = __builtin_amdgcn_mfma_f32_16x16x32_bf16(a1, w.bfrag[1][1], C1, 0, 0, 0);

    float partial;
    {
        float x0, x1, trow;
        x0 = C0[0] + w.b1c0; x0 = (x0 >= 0.f) ? x0 : 0.01f * x0;
        x1 = C1[0] + w.b1c1; x1 = (x1 >= 0.f) ? x1 : 0.01f * x1;
        trow = x0 * w.w2c0 + x1 * w.w2c1; partial  = trow * w.wh0;
        x0 = C0[1] + w.b1c0; x0 = (x0 >= 0.f) ? x0 : 0.01f * x0;
        x1 = C1[1] + w.b1c1; x1 = (x1 >= 0.f) ? x1 : 0.01f * x1;
        trow = x0 * w.w2c0 + x1 * w.w2c1; partial += trow * w.wh1;
        x0 = C0[2] + w.b1c0; x0 = (x0 >= 0.f) ? x0 : 0.01f * x0;
        x1 = C1[2] + w.b1c1; x1 = (x1 >= 0.f) ? x1 : 0.01f * x1;
        trow = x0 * w.w2c0 + x1 * w.w2c1; partial += trow * w.wh2;
        x0 = C0[3] + w.b1c0; x0 = (x0 >= 0.f) ? x0 : 0.01f * x0;
        x1 = C1[3] + w.b1c1; x1 = (x1 >= 0.f) ? x1 : 0.01f * x1;
        trow = x0 * w.w2c0 + x1 * w.w2c1; partial += trow * w.wh3;
    }
    partial += __shfl_xor(partial, 1);
    partial += __shfl_xor(partial, 2);
    partial += __shfl_xor(partial, 4);
    partial += __shfl_xor(partial, 8);
    partial += __shfl_xor(partial, 16);
    return partial + w.b2v * w.sumWh;
}

// K0: zero agg + ind + cnt
__global__ __launch_bounds__(256)
void init_kernel(float* __restrict__ agg, u32* __restrict__ ind, int* __restrict__ cnt,
                 int N3, int N)
{
    int i = blockIdx.x * blockDim.x + threadIdx.x;
    if (i < N3) agg[i] = 0.f;
    if (i < N)  ind[i] = 0u;
    if (i == 0) cnt[0] = 0;
}

// K1: ind[gidx[g]] = 1  (only agg at these nodes is ever read)
__global__ __launch_bounds__(256)
void mark_kernel(const void* __restrict__ gidxp, u32* __restrict__ ind,
                 const void* __restrict__ maskp, const void* __restrict__ eidxp, int G)
{
    const int lane = threadIdx.x & 63;
    int mbyte, i64f;
    detect_ints(maskp, eidxp, lane, mbyte, i64f);
    (void)mbyte;
    int g = blockIdx.x * blockDim.x + threadIdx.x;
    if (g >= G) return;
    const int idx = i64f ? (int)((const long long*)gidxp)[g] : ((const int*)gidxp)[g];
    ind[idx] = 1u;
}

// K2: lightweight scan (NO MFMA context): ballot-compact {eid, src, dst} of
//     edges that are valid AND whose src is gidx-marked.
__global__ __launch_bounds__(256)
void scan_kernel(const void* __restrict__ eidx,
                 const void* __restrict__ maskp,
                 const int*  __restrict__ proP,
                 const u32* __restrict__ ind,
                 int* __restrict__ cnt,
                 int* __restrict__ list,
                 int* __restrict__ srcl,
                 int* __restrict__ dstl,
                 int E)
{
    const int lane = threadIdx.x & 63;
    const int gw = blockIdx.x * 4 + (threadIdx.x >> 6);
    const int nchunks = (E + 63) >> 6;
    if (gw >= nchunks) return;

    const int base = gw << 6;
    const int ie = base + lane;

    const int*   e32 = (const int*)eidx;
    const long long* e64 = (const long long*)eidx;
    const unsigned char* m8 = (const unsigned char*)maskp;
    const int*   m32 = (const int*)maskp;

    int s32 = 0; long long s64 = 0; int m8v = 1;
    if (ie < E) { s32 = e32[ie]; s64 = e64[ie]; m8v = (int)m8[ie]; }
    const int pro = proP[0];

    int mbyte, i64f;
    detect_ints(maskp, eidx, lane, mbyte, i64f);

    const int srcv = i64f ? (int)s64 : s32;
    int mk = 1;
    if (ie < E) mk = mbyte ? m8v : m32[ie];
    const u32 need = ind[srcv];

    const bool v = (ie < E) && (srcv >= pro) && (mk == 0) && (need != 0u);
    const u64 bal = __ballot(v);
    const int nv = __popcll(bal);
    if (nv == 0) return;

    int basei = 0;
    if (lane == 0) basei = atomicAdd(cnt, nv);
    basei = __shfl(basei, 0);

    if (v) {
        const int off = __popcll(bal & ((1ull << lane) - 1ull));
        const int d = i64f ? (int)e64[E + ie] : e32[E + ie];
        list[basei + off] = ie;
        srcl[basei + off] = srcv;
        dstl[basei + off] = d;
    }
}

// K3: dense MFMA over compacted edges; 8 edges (4 tiles) per wave-iteration;
//     no LDS (att via butterfly halves + shfl); epilogue lanes 0-7.
__global__ __launch_bounds__(256, 4)
void dense_kernel(const void* __restrict__ a_ij,
                  const void* __restrict__ pos,
                  const void* __restrict__ W1p,
                  const void* __restrict__ b1p,
                  const void* __restrict__ W2p,
                  const void* __restrict__ b2p,
                  const void* __restrict__ Whp,
                  float* __restrict__ agg,
                  const int* __restrict__ cnt,
                  const int* __restrict__ list,
                  const int* __restrict__ srcl,
                  const int* __restrict__ dstl)
{
    const int lane = threadIdx.x & 63;
    const int gwave = blockIdx.x * 4 + (threadIdx.x >> 6);
    const int nw = gridDim.x * 4;

    const int count = cnt[0];
    if (gwave * 8 >= count) return;

    const WaveCtx w = setup_wave(lane, W1p, b1p, W2p, b2p, Whp);

    const float* a32 = (const float*)a_ij;
    const float* pp  = (const float*)pos;
    const int krow = (lane >> 4) * 8;
    const int row  = lane & 15;
    const int rsel = (row < 8) ? 0 : 1;

    for (int t = gwave; t * 8 < count; t += nw) {
        const int base8 = t * 8;
        const int np = min(8, count - base8);
        int slot = base8 + (lane & 7);
        if (slot > count - 1) slot = count - 1;

        const int eid  = list[slot];
        const int esrc = srcl[slot];
        const int edst = dstl[slot];

        // early pos gathers (lanes 0-7 use own slot), overlapped with a_ij loads
        float px = 0.f, py = 0.f, pz = 0.f, qx = 0.f, qy = 0.f, qz = 0.f;
        if (lane < np) {
            px = pp[3 * esrc]; py = pp[3 * esrc + 1]; pz = pp[3 * esrc + 2];
            qx = pp[3 * edst]; qy = pp[3 * edst + 1]; qz = pp[3 * edst + 2];
        }

        // tile k covers edges 2k (rows 0-7) and 2k+1 (rows 8-15)
        const int e0 = __shfl(eid, 0 + rsel);
        const int e1 = __shfl(eid, 2 + rsel);
        const int e2 = __shfl(eid, 4 + rsel);
        const int e3 = __shfl(eid, 6 + rsel);

        s8v x0, x1, y0, y1, z0, z1, u0, u1;
        load_tile(a32, e0, row, krow, x0, x1);
        load_tile(a32, e1, row, krow, y0, y1);
        load_tile(a32, e2, row, krow, z0, z1);
        load_tile(a32, e3, row, krow, u0, u1);

        const float at0 = tile_att(w, x0, x1);
        const float at1 = tile_att(w, y0, y1);
        const float at2 = tile_att(w, z0, z1);
        const float at3 = tile_att(w, u0, u1);
        const float at0o = __shfl(at0, 32);
        const float at1o = __shfl(at1, 32);
        const float at2o = __shfl(at2, 32);
        const float at3o = __shfl(at3, 32);

        if (lane < np) {
            const int k = lane >> 1;
            const float ate = (k == 0) ? at0 : (k == 1) ? at1 : (k == 2) ? at2 : at3;
            const float ato = (k == 0) ? at0o : (k == 1) ? at1o : (k == 2) ? at2o : at3o;
            const float att = (lane & 1) ? ato : ate;
            const float dx = px - qx, dy = py - qy, dz = pz - qz;
            const float nrm = sqrtf(dx * dx + dy * dy + dz * dz) + 1e-6f;
            const float sc = att / nrm;
            atomicAdd(&agg[3 * esrc + 0], dx * sc);
            atomicAdd(&agg[3 * esrc + 1], dy * sc);
            atomicAdd(&agg[3 * esrc + 2], dz * sc);
        }
    }
}

// K4: finalize
__global__ __launch_bounds__(256)
void finalize_kernel(const void* __restrict__ pos,
                     const void* __restrict__ gidxp,
                     const float* __restrict__ agg,
                     float* __restrict__ outp,
                     const void* __restrict__ maskp,
                     const void* __restrict__ eidxp,
                     int G)
{
    const int lane = threadIdx.x & 63;
    int mbyte, i64f;
    detect_ints(maskp, eidxp, lane, mbyte, i64f);
    (void)mbyte;

    int g = blockIdx.x * blockDim.x + threadIdx.x;
    if (g >= G) return;
    const int idx = i64f ? (int)((const long long*)gidxp)[g] : ((const int*)gidxp)[g];
    const float* pp = (const float*)pos;
    #pragma unroll
    for (int c = 0; c < 3; ++c) {
        outp[3 * g + c] = pp[3 * idx + c] + agg[3 * idx + c];
    }
}

extern "C" void kernel_launch(void* const* d_in, const int* in_sizes, int n_in,
                              void* d_out, int out_size, void* d_ws, size_t ws_size,
                              hipStream_t stream) {
    const void* a_ij = d_in[0];
    const void* pos  = d_in[1];
    const void* eidx = d_in[3];
    const void* gidx = d_in[5];
    const void* mask = d_in[6];
    const int*  pro  = (const int*)d_in[7];
    const void* W1   = d_in[8];
    const void* b1   = d_in[9];
    const void* W2   = d_in[10];
    const void* b2   = d_in[11];
    const void* Wh   = d_in[12];

    const int E  = in_sizes[3] / 2;
    const int N  = in_sizes[1] / 3;
    const int N3 = N * 3;
    const int G  = in_sizes[5];

    char* p = (char*)d_ws;
    float* agg = (float*)p;                 p += ((size_t)N3 * 4 + 255) & ~(size_t)255;
    u32*   ind = (u32*)p;                   p += ((size_t)N  * 4 + 255) & ~(size_t)255;
    int*   cnt = (int*)p;                   p += 256;
    int*   list = (int*)p;                  p += ((size_t)E * 4 + 255) & ~(size_t)255;
    int*   srcl = (int*)p;                  p += ((size_t)E * 4 + 255) & ~(size_t)255;
    int*   dstl = (int*)p;

    init_kernel<<<(N3 + 255) / 256, 256, 0, stream>>>(agg, ind, cnt, N3, N);

    mark_kernel<<<(G + 255) / 256, 256, 0, stream>>>(gidx, ind, mask, eidx, G);

    const int nchunks = (E + 63) >> 6;
    scan_kernel<<<(nchunks + 3) / 4, 256, 0, stream>>>(eidx, mask, pro, ind, cnt,
                                                       list, srcl, dstl, E);

    dense_kernel<<<512, 256, 0, stream>>>(a_ij, pos, W1, b1, W2, b2, Wh,
                                          agg, cnt, list, srcl, dstl);

    finalize_kernel<<<(G + 255) / 256, 256, 0, stream>>>(pos, gidx, agg, (float*)d_out,
                                                         mask, eidx, G);
}

// Round 17
// 27.387 us; speedup vs baseline: 3.1459x; 3.1459x over previous
//
#include <hip/hip_runtime.h>

typedef short s8v __attribute__((ext_vector_type(8)));
typedef float f4v __attribute__((ext_vector_type(4)));
typedef unsigned short u16;
typedef unsigned int   u32;
typedef unsigned long long u64;

#define NHEAD 8
#define FDIM  32   // D/2

__device__ __forceinline__ u16 f2bf(float f) {
    u32 u = __float_as_uint(f);
    u32 r = u + 0x7fffu + ((u >> 16) & 1u);   // round-to-nearest-even
    return (u16)(r >> 16);
}

// Int-width / mask-width detection (floats are f32: proven in R8/R9).
__device__ __forceinline__ void detect_ints(const void* maskp, const void* eidxp,
                                            int lane, int& mbyte, int& i64f) {
    u32 mkw = ((const u32*)maskp)[lane];
    mbyte = (__ballot(mkw > 1u) != 0ull) ? 1 : 0;       // byte-packed bools -> words > 1
    u32 od = ((const u32*)eidxp)[2 * lane + 1];
    i64f = (__ballot(od != 0u) == 0ull) ? 1 : 0;        // int64 -> odd words all zero
}

struct WaveCtx {
    s8v bfrag[2][2];
    float sumWh, b2v, b1c0, b1c1, w2c0, w2c1;
    float wh0, wh1, wh2, wh3;
};

__device__ __forceinline__ WaveCtx setup_wave(int lane,
    const void* W1p, const void* b1p, const void* W2p, const void* b2p, const void* Whp)
{
    WaveCtx w;
    const int c0 = lane & 15;
    const int krow = (lane >> 4) * 8;
    const int hi4  = (lane >> 4) & 1;
    const float* w1 = (const float*)W1p; const float* b1 = (const float*)b1p;
    const float* w2 = (const float*)W2p; const float* b2 = (const float*)b2p;
    const float* wh = (const float*)Whp;
    float WhV[NHEAD]; w.sumWh = 0.f;
    #pragma unroll
    for (int h = 0; h < NHEAD; ++h) { WhV[h] = wh[h]; w.sumWh += WhV[h]; }
    w.b2v = b2[0];
    w.b1c0 = b1[c0]; w.b1c1 = b1[c0 + 16];
    w.w2c0 = w2[c0]; w.w2c1 = w2[c0 + 16];
    #pragma unroll
    for (int cb = 0; cb < 2; ++cb)
        #pragma unroll
        for (int kh = 0; kh < 2; ++kh)
            #pragma unroll
            for (int j = 0; j < 8; ++j) {
                int k = kh * 32 + krow + j;
                w.bfrag[cb][kh][j] = (short)f2bf(w1[k * FDIM + cb * 16 + c0]);
            }
    w.wh0 = hi4 ? WhV[4] : WhV[0];
    w.wh1 = hi4 ? WhV[5] : WhV[1];
    w.wh2 = hi4 ? WhV[6] : WhV[2];
    w.wh3 = hi4 ? WhV[7] : WhV[3];
    return w;
}

__device__ __forceinline__ void load_tile(const float* a32, int edge, int row, int krow,
                                          s8v& a0, s8v& a1)
{
    const size_t rowbase = ((size_t)edge * 8 + (size_t)(row & 7)) * 64 + (size_t)krow;
    const f4v* p = (const f4v*)(a32 + rowbase);   // 32B-aligned
    f4v v0 = p[0], v1 = p[1], v2 = p[8], v3 = p[9];
    #pragma unroll
    for (int j = 0; j < 4; ++j) {
        a0[j]     = (short)f2bf(v0[j]);
        a0[j + 4] = (short)f2bf(v1[j]);
        a1[j]     = (short)f2bf(v2[j]);
        a1[j + 4] = (short)f2bf(v3[j]);
    }
}

// MFMA + MLP epilogue; att valid in all lanes (per 32-half's edge).
__device__ __forceinline__ float tile_att(const WaveCtx& w, const s8v& a0, const s8v& a1)
{
    f4v C0 = {0.f,0.f,0.f,0.f}, C1 = {0.f,0.f,0.f,0.f};
    C0 = __builtin_amdgcn_mfma_f32_16x16x32_bf16(a0, w.bfrag[0][0], C0, 0, 0, 0);
    C0 = __builtin_amdgcn_mfma_f32_16x16x32_bf16(a1, w.bfrag[0][1], C0, 0, 0, 0);
    C1 = __builtin_amdgcn_mfma_f32_16x16x32_bf16(a0, w.bfrag[1][0], C1, 0, 0, 0);
    C1 = __builtin_amdgcn_mfma_f32_16x16x32_bf16(a1, w.bfrag[1][1], C1, 0, 0, 0);

    float partial;
    {
        float x0, x1, trow;
        x0 = C0[0] + w.b1c0; x0 = (x0 >= 0.f) ? x0 : 0.01f * x0;
        x1 = C1[0] + w.b1c1; x1 = (x1 >= 0.f) ? x1 : 0.01f * x1;
        trow = x0 * w.w2c0 + x1 * w.w2c1; partial  = trow * w.wh0;
        x0 = C0[1] + w.b1c0; x0 = (x0 >= 0.f) ? x0 : 0.01f * x0;
        x1 = C1[1] + w.b1c1; x1 = (x1 >= 0.f) ? x1 : 0.01f * x1;
        trow = x0 * w.w2c0 + x1 * w.w2c1; partial += trow * w.wh1;
        x0 = C0[2] + w.b1c0; x0 = (x0 >= 0.f) ? x0 : 0.01f * x0;
        x1 = C1[2] + w.b1c1; x1 = (x1 >= 0.f) ? x1 : 0.01f * x1;
        trow = x0 * w.w2c0 + x1 * w.w2c1; partial += trow * w.wh2;
        x0 = C0[3] + w.b1c0; x0 = (x0 >= 0.f) ? x0 : 0.01f * x0;
        x1 = C1[3] + w.b1c1; x1 = (x1 >= 0.f) ? x1 : 0.01f * x1;
        trow = x0 * w.w2c0 + x1 * w.w2c1; partial += trow * w.wh3;
    }
    partial += __shfl_xor(partial, 1);
    partial += __shfl_xor(partial, 2);
    partial += __shfl_xor(partial, 4);
    partial += __shfl_xor(partial, 8);
    partial += __shfl_xor(partial, 16);
    return partial + w.b2v * w.sumWh;
}

// K1: zero agg + indicator
__global__ __launch_bounds__(256)
void zero_kernel(float* __restrict__ agg, u32* __restrict__ ind, int N3, int N)
{
    int i = blockIdx.x * blockDim.x + threadIdx.x;
    if (i < N3) agg[i] = 0.f;
    if (i < N)  ind[i] = 0u;
}

// K1b: scatter indicator: ind[gidx[g]] = 1  (only agg at these nodes is read)
__global__ __launch_bounds__(256)
void mark_kernel(const void* __restrict__ gidxp, u32* __restrict__ ind,
                 const void* __restrict__ maskp, const void* __restrict__ eidxp, int G)
{
    const int lane = threadIdx.x & 63;
    int mbyte, i64f;
    detect_ints(maskp, eidxp, lane, mbyte, i64f);
    (void)mbyte;
    int g = blockIdx.x * blockDim.x + threadIdx.x;
    if (g >= G) return;
    const int idx = i64f ? (int)((const long long*)gidxp)[g] : ((const int*)gidxp)[g];
    ind[idx] = 1u;
}

// K2: one 64-edge chunk per wave; validity includes ind[src] (dead-edge cull);
//     ballot-compact; 2-tile batches; early pos-gathers; parallel epilogue.
//     (Proven best: R15, 26.7 us.)
__global__ __launch_bounds__(256, 4)
void attn_kernel(const void* __restrict__ a_ij,
                 const void* __restrict__ pos,
                 const void* __restrict__ eidx,
                 const void* __restrict__ maskp,
                 const int*  __restrict__ proP,
                 const void* __restrict__ W1p,
                 const void* __restrict__ b1p,
                 const void* __restrict__ W2p,
                 const void* __restrict__ b2p,
                 const void* __restrict__ Whp,
                 float* __restrict__ agg,
                 const u32* __restrict__ ind,
                 int E)
{
    __shared__ float attbuf[4][68];
    __shared__ int   idxbuf[4][68];

    const int lane = threadIdx.x & 63;
    const int wv   = threadIdx.x >> 6;
    const int gw = blockIdx.x * 4 + wv;
    const int nchunks = (E + 63) >> 6;
    if (gw >= nchunks) return;

    const int base = gw << 6;
    const int ie = base + lane;

    const int*   e32 = (const int*)eidx;
    const long long* e64 = (const long long*)eidx;
    const unsigned char* m8 = (const unsigned char*)maskp;
    const int*   m32 = (const int*)maskp;

    // speculative loads, all in-bounds under either int width
    int s32 = 0; long long s64 = 0; int m8v = 1;
    if (ie < E) { s32 = e32[ie]; s64 = e64[ie]; m8v = (int)m8[ie]; }
    const int pro = proP[0];

    int mbyte, i64f;
    detect_ints(maskp, eidx, lane, mbyte, i64f);

    const int srcv = i64f ? (int)s64 : s32;
    int mk = 1;
    if (ie < E) mk = mbyte ? m8v : m32[ie];

    // indicator gather (L2-resident 160KB): edge matters only if agg[src] is read
    const u32 need = ind[srcv];

    // scalar-heavy setup overlaps outstanding load latency
    const WaveCtx w = setup_wave(lane, W1p, b1p, W2p, b2p, Whp);

    const bool v = (ie < E) && (srcv >= pro) && (mk == 0) && (need != 0u);
    const u64 msav = __ballot(v);
    const int nv = __popcll(msav);
    if (nv == 0) return;

    // ordinal -> lane map (O(1) epilogue indexing)
    const int off = __popcll(msav & ((1ull << lane) - 1ull));
    if (v) idxbuf[wv][off] = lane;
    asm volatile("s_waitcnt lgkmcnt(0)" ::: "memory");

    const int bp = idxbuf[wv][(lane < nv) ? lane : 0] & 63;
    const int s  = __shfl(srcv, bp);

    // early epilogue gathers: issued before MFMA work, consumed after
    float px = 0.f, py = 0.f, pz = 0.f, qx = 0.f, qy = 0.f, qz = 0.f;
    if (lane < nv) {
        const int e = base + bp;
        const int d = i64f ? (int)e64[E + e] : e32[E + e];
        const float* pp = (const float*)pos;
        px = pp[3 * s]; py = pp[3 * s + 1]; pz = pp[3 * s + 2];
        qx = pp[3 * d]; qy = pp[3 * d + 1]; qz = pp[3 * d + 2];
    }

    // ---- 2-tile (4-edge) batches ----
    const float* a32 = (const float*)a_ij;
    const int krow = (lane >> 4) * 8;
    const int row  = lane & 15;

    u64 m0 = msav;
    auto pop = [&](int& dst) -> bool {
        if (m0) { dst = __builtin_ctzll(m0); m0 &= m0 - 1; return true; }
        return false;
    };

    int slot = 0;
    while (m0) {
        int ba, bb, bc, bd;
        pop(ba);
        bool h1 = pop(bb); if (!h1) bb = ba;
        bool h2 = pop(bc);
        bool h3 = false;
        if (h2) { h3 = pop(bd); if (!h3) bd = bc; }

        s8v x0, x1, y0, y1;
        load_tile(a32, base + ((row < 8) ? ba : bb), row, krow, x0, x1);
        if (h2) load_tile(a32, base + ((row < 8) ? bc : bd), row, krow, y0, y1);

        const float atA = tile_att(w, x0, x1);
        if ((lane & 31) == 0) attbuf[wv][slot + (lane >> 5)] = atA;
        int adv = 1 + (h1 ? 1 : 0);
        if (h2) {
            const float atB = tile_att(w, y0, y1);
            if ((lane & 31) == 0) attbuf[wv][slot + adv + (lane >> 5)] = atB;
            adv += 1 + (h3 ? 1 : 0);
        }
        slot += adv;
    }

    asm volatile("s_waitcnt lgkmcnt(0)" ::: "memory");

    // ---- parallel scatter epilogue: lane i handles i-th valid edge ----
    if (lane < nv) {
        const float att = attbuf[wv][lane];
        const float dx = px - qx, dy = py - qy, dz = pz - qz;
        const float nrm = sqrtf(dx * dx + dy * dy + dz * dz) + 1e-6f;
        const float sc = att / nrm;
        atomicAdd(&agg[3 * s + 0], dx * sc);
        atomicAdd(&agg[3 * s + 1], dy * sc);
        atomicAdd(&agg[3 * s + 2], dz * sc);
    }
}

// K3: finalize
__global__ __launch_bounds__(256)
void finalize_kernel(const void* __restrict__ pos,
                     const void* __restrict__ gidxp,
                     const float* __restrict__ agg,
                     float* __restrict__ outp,
                     const void* __restrict__ maskp,
                     const void* __restrict__ eidxp,
                     int G)
{
    const int lane = threadIdx.x & 63;
    int mbyte, i64f;
    detect_ints(maskp, eidxp, lane, mbyte, i64f);
    (void)mbyte;

    int g = blockIdx.x * blockDim.x + threadIdx.x;
    if (g >= G) return;
    const int idx = i64f ? (int)((const long long*)gidxp)[g] : ((const int*)gidxp)[g];
    const float* pp = (const float*)pos;
    #pragma unroll
    for (int c = 0; c < 3; ++c) {
        outp[3 * g + c] = pp[3 * idx + c] + agg[3 * idx + c];
    }
}

extern "C" void kernel_launch(void* const* d_in, const int* in_sizes, int n_in,
                              void* d_out, int out_size, void* d_ws, size_t ws_size,
                              hipStream_t stream) {
    const void* a_ij = d_in[0];
    const void* pos  = d_in[1];
    const void* eidx = d_in[3];
    const void* gidx = d_in[5];
    const void* mask = d_in[6];
    const int*  pro  = (const int*)d_in[7];
    const void* W1   = d_in[8];
    const void* b1   = d_in[9];
    const void* W2   = d_in[10];
    const void* b2   = d_in[11];
    const void* Wh   = d_in[12];

    const int E  = in_sizes[3] / 2;
    const int N  = in_sizes[1] / 3;
    const int N3 = N * 3;
    const int G  = in_sizes[5];

    float* agg = (float*)d_ws;
    u32*   ind = (u32*)((char*)d_ws + (((size_t)N3 * 4 + 255) & ~(size_t)255));

    zero_kernel<<<(N3 + 255) / 256, 256, 0, stream>>>(agg, ind, N3, N);

    mark_kernel<<<(G + 255) / 256, 256, 0, stream>>>(gidx, ind, mask, eidx, G);

    const int nchunks = (E + 63) >> 6;            // one 64-edge chunk per wave
    const int nblocks = (nchunks + 3) / 4;        // 4 waves per block
    attn_kernel<<<nblocks, 256, 0, stream>>>(a_ij, pos, eidx, mask, pro,
                                             W1, b1, W2, b2, Wh, agg, ind, E);

    finalize_kernel<<<(G + 255) / 256, 256, 0, stream>>>(pos, gidx, agg, (float*)d_out,
                                                         mask, eidx, G);
}

// Round 18
// 24.951 us; speedup vs baseline: 3.4530x; 1.0976x over previous
//
#include <hip/hip_runtime.h>

typedef short s8v __attribute__((ext_vector_type(8)));
typedef float f4v __attribute__((ext_vector_type(4)));
typedef unsigned short u16;
typedef unsigned int   u32;
typedef unsigned long long u64;

#define NHEAD 8
#define FDIM  32   // D/2

__device__ __forceinline__ u16 f2bf(float f) {
    u32 u = __float_as_uint(f);
    u32 r = u + 0x7fffu + ((u >> 16) & 1u);   // round-to-nearest-even
    return (u16)(r >> 16);
}

// Int-width / mask-width detection (floats are f32: proven in R8/R9).
__device__ __forceinline__ void detect_ints(const void* maskp, const void* eidxp,
                                            int lane, int& mbyte, int& i64f) {
    u32 mkw = ((const u32*)maskp)[lane];
    mbyte = (__ballot(mkw > 1u) != 0ull) ? 1 : 0;       // byte-packed bools -> words > 1
    u32 od = ((const u32*)eidxp)[2 * lane + 1];
    i64f = (__ballot(od != 0u) == 0ull) ? 1 : 0;        // int64 -> odd words all zero
}

struct WaveCtx {
    s8v bfrag[2][2];
    float sumWh, b2v, b1c0, b1c1, w2c0, w2c1;
    float wh0, wh1, wh2, wh3;
};

__device__ __forceinline__ WaveCtx setup_wave(int lane,
    const void* W1p, const void* b1p, const void* W2p, const void* b2p, const void* Whp)
{
    WaveCtx w;
    const int c0 = lane & 15;
    const int krow = (lane >> 4) * 8;
    const int hi4  = (lane >> 4) & 1;
    const float* w1 = (const float*)W1p; const float* b1 = (const float*)b1p;
    const float* w2 = (const float*)W2p; const float* b2 = (const float*)b2p;
    const float* wh = (const float*)Whp;
    float WhV[NHEAD]; w.sumWh = 0.f;
    #pragma unroll
    for (int h = 0; h < NHEAD; ++h) { WhV[h] = wh[h]; w.sumWh += WhV[h]; }
    w.b2v = b2[0];
    w.b1c0 = b1[c0]; w.b1c1 = b1[c0 + 16];
    w.w2c0 = w2[c0]; w.w2c1 = w2[c0 + 16];
    #pragma unroll
    for (int cb = 0; cb < 2; ++cb)
        #pragma unroll
        for (int kh = 0; kh < 2; ++kh)
            #pragma unroll
            for (int j = 0; j < 8; ++j) {
                int k = kh * 32 + krow + j;
                w.bfrag[cb][kh][j] = (short)f2bf(w1[k * FDIM + cb * 16 + c0]);
            }
    w.wh0 = hi4 ? WhV[4] : WhV[0];
    w.wh1 = hi4 ? WhV[5] : WhV[1];
    w.wh2 = hi4 ? WhV[6] : WhV[2];
    w.wh3 = hi4 ? WhV[7] : WhV[3];
    return w;
}

__device__ __forceinline__ void load_tile(const float* a32, int edge, int row, int krow,
                                          s8v& a0, s8v& a1)
{
    const size_t rowbase = ((size_t)edge * 8 + (size_t)(row & 7)) * 64 + (size_t)krow;
    const f4v* p = (const f4v*)(a32 + rowbase);   // 32B-aligned
    f4v v0 = p[0], v1 = p[1], v2 = p[8], v3 = p[9];
    #pragma unroll
    for (int j = 0; j < 4; ++j) {
        a0[j]     = (short)f2bf(v0[j]);
        a0[j + 4] = (short)f2bf(v1[j]);
        a1[j]     = (short)f2bf(v2[j]);
        a1[j + 4] = (short)f2bf(v3[j]);
    }
}

// MFMA + MLP epilogue; att valid in all lanes (per 32-half's edge).
__device__ __forceinline__ float tile_att(const WaveCtx& w, const s8v& a0, const s8v& a1)
{
    f4v C0 = {0.f,0.f,0.f,0.f}, C1 = {0.f,0.f,0.f,0.f};
    C0 = __builtin_amdgcn_mfma_f32_16x16x32_bf16(a0, w.bfrag[0][0], C0, 0, 0, 0);
    C0 = __builtin_amdgcn_mfma_f32_16x16x32_bf16(a1, w.bfrag[0][1], C0, 0, 0, 0);
    C1 = __builtin_amdgcn_mfma_f32_16x16x32_bf16(a0, w.bfrag[1][0], C1, 0, 0, 0);
    C1 = __builtin_amdgcn_mfma_f32_16x16x32_bf16(a1, w.bfrag[1][1], C1, 0, 0, 0);

    float partial;
    {
        float x0, x1, trow;
        x0 = C0[0] + w.b1c0; x0 = (x0 >= 0.f) ? x0 : 0.01f * x0;
        x1 = C1[0] + w.b1c1; x1 = (x1 >= 0.f) ? x1 : 0.01f * x1;
        trow = x0 * w.w2c0 + x1 * w.w2c1; partial  = trow * w.wh0;
        x0 = C0[1] + w.b1c0; x0 = (x0 >= 0.f) ? x0 : 0.01f * x0;
        x1 = C1[1] + w.b1c1; x1 = (x1 >= 0.f) ? x1 : 0.01f * x1;
        trow = x0 * w.w2c0 + x1 * w.w2c1; partial += trow * w.wh1;
        x0 = C0[2] + w.b1c0; x0 = (x0 >= 0.f) ? x0 : 0.01f * x0;
        x1 = C1[2] + w.b1c1; x1 = (x1 >= 0.f) ? x1 : 0.01f * x1;
        trow = x0 * w.w2c0 + x1 * w.w2c1; partial += trow * w.wh2;
        x0 = C0[3] + w.b1c0; x0 = (x0 >= 0.f) ? x0 : 0.01f * x0;
        x1 = C1[3] + w.b1c1; x1 = (x1 >= 0.f) ? x1 : 0.01f * x1;
        trow = x0 * w.w2c0 + x1 * w.w2c1; partial += trow * w.wh3;
    }
    partial += __shfl_xor(partial, 1);
    partial += __shfl_xor(partial, 2);
    partial += __shfl_xor(partial, 4);
    partial += __shfl_xor(partial, 8);
    partial += __shfl_xor(partial, 16);
    return partial + w.b2v * w.sumWh;
}

// K1: mark + targeted zero. ind[gidx[g]] = 1 and agg[3*gidx[g)..+2] = 0.
// ind is never globally zeroed: marks are identical every launch (same gidx),
// 0xAA poison != 1 culls correctly, and stale==1 garbage only *includes* extra
// edges whose agg entries are never read (harmless). agg is zeroed exactly at
// the positions finalize reads.
__global__ __launch_bounds__(256)
void mark_kernel(const void* __restrict__ gidxp, u32* __restrict__ ind,
                 float* __restrict__ agg,
                 const void* __restrict__ maskp, const void* __restrict__ eidxp, int G)
{
    const int lane = threadIdx.x & 63;
    int mbyte, i64f;
    detect_ints(maskp, eidxp, lane, mbyte, i64f);
    (void)mbyte;
    int g = blockIdx.x * blockDim.x + threadIdx.x;
    if (g >= G) return;
    const int idx = i64f ? (int)((const long long*)gidxp)[g] : ((const int*)gidxp)[g];
    ind[idx] = 1u;
    agg[3 * idx + 0] = 0.f;
    agg[3 * idx + 1] = 0.f;
    agg[3 * idx + 2] = 0.f;
}

// K2: one 64-edge chunk per wave; validity includes ind[src]==1 (dead-edge cull);
//     ballot-compact; 2-tile batches; early pos-gathers; parallel epilogue.
__global__ __launch_bounds__(256, 4)
void attn_kernel(const void* __restrict__ a_ij,
                 const void* __restrict__ pos,
                 const void* __restrict__ eidx,
                 const void* __restrict__ maskp,
                 const int*  __restrict__ proP,
                 const void* __restrict__ W1p,
                 const void* __restrict__ b1p,
                 const void* __restrict__ W2p,
                 const void* __restrict__ b2p,
                 const void* __restrict__ Whp,
                 float* __restrict__ agg,
                 const u32* __restrict__ ind,
                 int E)
{
    __shared__ float attbuf[4][68];
    __shared__ int   idxbuf[4][68];

    const int lane = threadIdx.x & 63;
    const int wv   = threadIdx.x >> 6;
    const int gw = blockIdx.x * 4 + wv;
    const int nchunks = (E + 63) >> 6;
    if (gw >= nchunks) return;

    const int base = gw << 6;
    const int ie = base + lane;

    const int*   e32 = (const int*)eidx;
    const long long* e64 = (const long long*)eidx;
    const unsigned char* m8 = (const unsigned char*)maskp;
    const int*   m32 = (const int*)maskp;

    // speculative loads, all in-bounds under either int width
    int s32 = 0; long long s64 = 0; int m8v = 1;
    if (ie < E) { s32 = e32[ie]; s64 = e64[ie]; m8v = (int)m8[ie]; }
    const int pro = proP[0];

    int mbyte, i64f;
    detect_ints(maskp, eidx, lane, mbyte, i64f);

    const int srcv = i64f ? (int)s64 : s32;
    int mk = 1;
    if (ie < E) mk = mbyte ? m8v : m32[ie];

    // indicator gather (L2-resident 160KB): edge matters only if agg[src] is read
    const u32 need = ind[srcv];

    // scalar-heavy setup overlaps outstanding load latency
    const WaveCtx w = setup_wave(lane, W1p, b1p, W2p, b2p, Whp);

    const bool v = (ie < E) && (srcv >= pro) && (mk == 0) && (need == 1u);
    const u64 msav = __ballot(v);
    const int nv = __popcll(msav);
    if (nv == 0) return;

    // ordinal -> lane map (O(1) epilogue indexing)
    const int off = __popcll(msav & ((1ull << lane) - 1ull));
    if (v) idxbuf[wv][off] = lane;
    asm volatile("s_waitcnt lgkmcnt(0)" ::: "memory");

    const int bp = idxbuf[wv][(lane < nv) ? lane : 0] & 63;
    const int s  = __shfl(srcv, bp);

    // early epilogue gathers: issued before MFMA work, consumed after
    float px = 0.f, py = 0.f, pz = 0.f, qx = 0.f, qy = 0.f, qz = 0.f;
    if (lane < nv) {
        const int e = base + bp;
        const int d = i64f ? (int)e64[E + e] : e32[E + e];
        const float* pp = (const float*)pos;
        px = pp[3 * s]; py = pp[3 * s + 1]; pz = pp[3 * s + 2];
        qx = pp[3 * d]; qy = pp[3 * d + 1]; qz = pp[3 * d + 2];
    }

    // ---- 2-tile (4-edge) batches ----
    const float* a32 = (const float*)a_ij;
    const int krow = (lane >> 4) * 8;
    const int row  = lane & 15;

    u64 m0 = msav;
    auto pop = [&](int& dst) -> bool {
        if (m0) { dst = __builtin_ctzll(m0); m0 &= m0 - 1; return true; }
        return false;
    };

    int slot = 0;
    while (m0) {
        int ba, bb, bc, bd;
        pop(ba);
        bool h1 = pop(bb); if (!h1) bb = ba;
        bool h2 = pop(bc);
        bool h3 = false;
        if (h2) { h3 = pop(bd); if (!h3) bd = bc; }

        s8v x0, x1, y0, y1;
        load_tile(a32, base + ((row < 8) ? ba : bb), row, krow, x0, x1);
        if (h2) load_tile(a32, base + ((row < 8) ? bc : bd), row, krow, y0, y1);

        const float atA = tile_att(w, x0, x1);
        if ((lane & 31) == 0) attbuf[wv][slot + (lane >> 5)] = atA;
        int adv = 1 + (h1 ? 1 : 0);
        if (h2) {
            const float atB = tile_att(w, y0, y1);
            if ((lane & 31) == 0) attbuf[wv][slot + adv + (lane >> 5)] = atB;
            adv += 1 + (h3 ? 1 : 0);
        }
        slot += adv;
    }

    asm volatile("s_waitcnt lgkmcnt(0)" ::: "memory");

    // ---- parallel scatter epilogue: lane i handles i-th valid edge ----
    if (lane < nv) {
        const float att = attbuf[wv][lane];
        const float dx = px - qx, dy = py - qy, dz = pz - qz;
        const float nrm = sqrtf(dx * dx + dy * dy + dz * dz) + 1e-6f;
        const float sc = att / nrm;
        atomicAdd(&agg[3 * s + 0], dx * sc);
        atomicAdd(&agg[3 * s + 1], dy * sc);
        atomicAdd(&agg[3 * s + 2], dz * sc);
    }
}

// K3: finalize
__global__ __launch_bounds__(256)
void finalize_kernel(const void* __restrict__ pos,
                     const void* __restrict__ gidxp,
                     const float* __restrict__ agg,
                     float* __restrict__ outp,
                     const void* __restrict__ maskp,
                     const void* __restrict__ eidxp,
                     int G)
{
    const int lane = threadIdx.x & 63;
    int mbyte, i64f;
    detect_ints(maskp, eidxp, lane, mbyte, i64f);
    (void)mbyte;

    int g = blockIdx.x * blockDim.x + threadIdx.x;
    if (g >= G) return;
    const int idx = i64f ? (int)((const long long*)gidxp)[g] : ((const int*)gidxp)[g];
    const float* pp = (const float*)pos;
    #pragma unroll
    for (int c = 0; c < 3; ++c) {
        outp[3 * g + c] = pp[3 * idx + c] + agg[3 * idx + c];
    }
}

extern "C" void kernel_launch(void* const* d_in, const int* in_sizes, int n_in,
                              void* d_out, int out_size, void* d_ws, size_t ws_size,
                              hipStream_t stream) {
    const void* a_ij = d_in[0];
    const void* pos  = d_in[1];
    const void* eidx = d_in[3];
    const void* gidx = d_in[5];
    const void* mask = d_in[6];
    const int*  pro  = (const int*)d_in[7];
    const void* W1   = d_in[8];
    const void* b1   = d_in[9];
    const void* W2   = d_in[10];
    const void* b2   = d_in[11];
    const void* Wh   = d_in[12];

    const int E  = in_sizes[3] / 2;
    const int N  = in_sizes[1] / 3;
    const int N3 = N * 3;
    const int G  = in_sizes[5];

    float* agg = (float*)d_ws;
    u32*   ind = (u32*)((char*)d_ws + (((size_t)N3 * 4 + 255) & ~(size_t)255));

    mark_kernel<<<(G + 255) / 256, 256, 0, stream>>>(gidx, ind, agg, mask, eidx, G);

    const int nchunks = (E + 63) >> 6;            // one 64-edge chunk per wave
    const int nblocks = (nchunks + 3) / 4;        // 4 waves per block
    attn_kernel<<<nblocks, 256, 0, stream>>>(a_ij, pos, eidx, mask, pro,
                                             W1, b1, W2, b2, Wh, agg, ind, E);

    finalize_kernel<<<(G + 255) / 256, 256, 0, stream>>>(pos, gidx, agg, (float*)d_out,
                                                         mask, eidx, G);
}